// Round 3
// baseline (657.373 us; speedup 1.0000x reference)
//
#include <hip/hip_runtime.h>
#include <hip/hip_bf16.h>
#include <stdint.h>

typedef __bf16 bf16;
typedef __attribute__((ext_vector_type(8))) __bf16 bf16x8;
typedef __attribute__((ext_vector_type(4))) float f32x4;

constexpr int S  = 2048;
constexpr int DH = 64;
constexpr int BQ = 16;           // q-rows per block

// Fragment conventions (verified by round-1/2 passing kernel):
//   mfma(X, Y, acc): X lane(c,g) = X[i=c][k=g*8+j]; Y lane(c,g) = Y[j2=c][k=g*8+j]
//   D lane(c,g) reg r = D[i=g*4+r][j2=c],  D = X · Y^T
// Swapped QK^T: mfma(Kfrag, Qfrag) -> lane(c,g) reg r = P[key=k0+4g+r][q=c]
//   => every lane owns ONE q-row (q=c); keys are contiguous per reg quad.

__global__ __launch_bounds__(256, 4)
void attn_fused(const float* __restrict__ Q, const float* __restrict__ K,
                const float* __restrict__ V, const float* __restrict__ Msk,
                float* __restrict__ Out, float* __restrict__ W)
{
    __shared__ float rs[4][BQ];          // per-wave row-sum partials
    __shared__ float inv[BQ];            // 1/rowsum
    __shared__ float opart[4][BQ][DH];   // per-wave O partials (16 KB)

    const int tid  = threadIdx.x;
    const int lane = tid & 63;
    const int wave = tid >> 6;           // 0..3
    const int c    = lane & 15;
    const int g    = lane >> 4;          // 0..3

    // XCD-aware swizzle: XCD x gets 512 consecutive swz -> 4 contiguous bh (K+V = 4MB in its L2)
    const int swz = (blockIdx.x & 7) * 512 + (blockIdx.x >> 3);
    const int bh = swz >> 7;             // 0..31
    const int q0 = (swz & 127) * BQ;

    const float* Qb = Q + (size_t)bh * S * DH;
    const float* Kb = K + (size_t)bh * S * DH;
    const float* Vb = V + (size_t)bh * S * DH;

    // ---- Q fragment (Y-operand): lane(c,g) = Q[q0+c][g*8+j], dh halves lo/hi
    bf16x8 qlo, qhi;
    {
        const float* qr = Qb + (size_t)(q0 + c) * DH + g * 8;
        f32x4 a0 = *(const f32x4*)(qr);
        f32x4 a1 = *(const f32x4*)(qr + 4);
        f32x4 b0 = *(const f32x4*)(qr + 32);
        f32x4 b1 = *(const f32x4*)(qr + 36);
        #pragma unroll
        for (int j = 0; j < 4; ++j) {
            qlo[j]     = (bf16)a0[j];  qlo[j + 4] = (bf16)a1[j];
            qhi[j]     = (bf16)b0[j];  qhi[j + 4] = (bf16)b1[j];
        }
    }

    const int kbase = wave * (S / 4);                 // wave owns 512 keys
    const float* mrow = Msk + (size_t)(q0 + c) * S;   // this lane's q-row of the mask

    // =========== Pass A: row sums (max-free softmax; logits are data-bounded) ===========
    float s = 0.f;
    for (int kc = 0; kc < 16; ++kc) {
        const int k0 = kbase + kc * 32;
        const float* kr0 = Kb + (size_t)(k0 + c) * DH + g * 8;
        const float* kr1 = kr0 + (size_t)16 * DH;
        f32x4 a0 = *(const f32x4*)(kr0);
        f32x4 a1 = *(const f32x4*)(kr0 + 4);
        f32x4 b0 = *(const f32x4*)(kr0 + 32);
        f32x4 b1 = *(const f32x4*)(kr0 + 36);
        f32x4 a2 = *(const f32x4*)(kr1);
        f32x4 a3 = *(const f32x4*)(kr1 + 4);
        f32x4 b2 = *(const f32x4*)(kr1 + 32);
        f32x4 b3 = *(const f32x4*)(kr1 + 36);
        f32x4 m0 = *(const f32x4*)(mrow + k0 + 4 * g);
        f32x4 m1 = *(const f32x4*)(mrow + k0 + 16 + 4 * g);

        bf16x8 kl0, kh0, kl1, kh1;
        #pragma unroll
        for (int j = 0; j < 4; ++j) {
            kl0[j] = (bf16)a0[j];  kl0[j + 4] = (bf16)a1[j];
            kh0[j] = (bf16)b0[j];  kh0[j + 4] = (bf16)b1[j];
            kl1[j] = (bf16)a2[j];  kl1[j + 4] = (bf16)a3[j];
            kh1[j] = (bf16)b2[j];  kh1[j + 4] = (bf16)b3[j];
        }
        f32x4 acc0 = {0.f, 0.f, 0.f, 0.f};
        f32x4 acc1 = {0.f, 0.f, 0.f, 0.f};
        acc0 = __builtin_amdgcn_mfma_f32_16x16x32_bf16(kl0, qlo, acc0, 0, 0, 0);
        acc0 = __builtin_amdgcn_mfma_f32_16x16x32_bf16(kh0, qhi, acc0, 0, 0, 0);
        acc1 = __builtin_amdgcn_mfma_f32_16x16x32_bf16(kl1, qlo, acc1, 0, 0, 0);
        acc1 = __builtin_amdgcn_mfma_f32_16x16x32_bf16(kh1, qhi, acc1, 0, 0, 0);
        #pragma unroll
        for (int r = 0; r < 4; ++r) {
            s += __expf(acc0[r] * 0.125f + m0[r] * (-1e9f));
            s += __expf(acc1[r] * 0.125f + m1[r] * (-1e9f));
        }
    }
    // reduce over g-groups (same q=c), then across waves
    s += __shfl_xor(s, 16);
    s += __shfl_xor(s, 32);
    if (lane < 16) rs[wave][lane] = s;
    __syncthreads();
    if (tid < BQ) inv[tid] = 1.f / (rs[0][tid] + rs[1][tid] + rs[2][tid] + rs[3][tid]);
    __syncthreads();
    const float myinv = inv[c];

    // =========== Pass B: recompute P, write W (f32, normalized), accumulate PV ===========
    f32x4 oacc[4] = {{0,0,0,0},{0,0,0,0},{0,0,0,0},{0,0,0,0}};
    float* Wrow = W + (size_t)bh * S * S + (size_t)(q0 + c) * S;   // this lane's W row

    for (int kc = 0; kc < 16; ++kc) {
        const int k0 = kbase + kc * 32;

        // --- issue V loads early (independent of P): rows k0+4g+j / k0+16+4g+j, cols c+16*dt
        const float* vp0 = Vb + (size_t)(k0 + 4 * g) * DH + c;
        const float* vp1 = vp0 + (size_t)16 * DH;
        float vv[4][8];
        #pragma unroll
        for (int j = 0; j < 4; ++j) {
            #pragma unroll
            for (int dt = 0; dt < 4; ++dt) {
                vv[dt][j]     = vp0[j * DH + dt * 16];
                vv[dt][j + 4] = vp1[j * DH + dt * 16];
            }
        }

        // --- K + mask loads
        const float* kr0 = Kb + (size_t)(k0 + c) * DH + g * 8;
        const float* kr1 = kr0 + (size_t)16 * DH;
        f32x4 a0 = *(const f32x4*)(kr0);
        f32x4 a1 = *(const f32x4*)(kr0 + 4);
        f32x4 b0 = *(const f32x4*)(kr0 + 32);
        f32x4 b1 = *(const f32x4*)(kr0 + 36);
        f32x4 a2 = *(const f32x4*)(kr1);
        f32x4 a3 = *(const f32x4*)(kr1 + 4);
        f32x4 b2 = *(const f32x4*)(kr1 + 32);
        f32x4 b3 = *(const f32x4*)(kr1 + 36);
        f32x4 m0 = *(const f32x4*)(mrow + k0 + 4 * g);
        f32x4 m1 = *(const f32x4*)(mrow + k0 + 16 + 4 * g);

        bf16x8 kl0, kh0, kl1, kh1;
        #pragma unroll
        for (int j = 0; j < 4; ++j) {
            kl0[j] = (bf16)a0[j];  kl0[j + 4] = (bf16)a1[j];
            kh0[j] = (bf16)b0[j];  kh0[j + 4] = (bf16)b1[j];
            kl1[j] = (bf16)a2[j];  kl1[j + 4] = (bf16)a3[j];
            kh1[j] = (bf16)b2[j];  kh1[j + 4] = (bf16)b3[j];
        }
        f32x4 acc0 = {0.f, 0.f, 0.f, 0.f};
        f32x4 acc1 = {0.f, 0.f, 0.f, 0.f};
        acc0 = __builtin_amdgcn_mfma_f32_16x16x32_bf16(kl0, qlo, acc0, 0, 0, 0);
        acc0 = __builtin_amdgcn_mfma_f32_16x16x32_bf16(kh0, qhi, acc0, 0, 0, 0);
        acc1 = __builtin_amdgcn_mfma_f32_16x16x32_bf16(kl1, qlo, acc1, 0, 0, 0);
        acc1 = __builtin_amdgcn_mfma_f32_16x16x32_bf16(kh1, qhi, acc1, 0, 0, 0);

        // --- exp (unnormalized P), lane owns q=c, keys k0+4g+r / k0+16+4g+r
        float p0[4], p1[4];
        #pragma unroll
        for (int r = 0; r < 4; ++r) {
            p0[r] = __expf(acc0[r] * 0.125f + m0[r] * (-1e9f));
            p1[r] = __expf(acc1[r] * 0.125f + m1[r] * (-1e9f));
        }

        // --- W write: f32x4 at contiguous keys, normalized; nontemporal (don't thrash L2)
        f32x4 w0 = { p0[0] * myinv, p0[1] * myinv, p0[2] * myinv, p0[3] * myinv };
        f32x4 w1 = { p1[0] * myinv, p1[1] * myinv, p1[2] * myinv, p1[3] * myinv };
        __builtin_nontemporal_store(w0, (f32x4*)(Wrow + k0 + 4 * g));
        __builtin_nontemporal_store(w1, (f32x4*)(Wrow + k0 + 16 + 4 * g));

        // --- pack PV A-fragment: slot (g,j) holds key kA = k0+4g+j (j<4) / k0+16+4g+(j-4)
        bf16x8 pa;
        #pragma unroll
        for (int j = 0; j < 4; ++j) {
            pa[j]     = (bf16)p0[j];
            pa[j + 4] = (bf16)p1[j];
        }
        // --- V B-fragments use the SAME key permutation; 4 d-tiles of 16 cols
        #pragma unroll
        for (int dt = 0; dt < 4; ++dt) {
            bf16x8 vb;
            #pragma unroll
            for (int j = 0; j < 8; ++j) vb[j] = (bf16)vv[dt][j];
            oacc[dt] = __builtin_amdgcn_mfma_f32_16x16x32_bf16(pa, vb, oacc[dt], 0, 0, 0);
        }
    }

    // --- cross-wave O reduction: lane(c,g) reg r of oacc[dt] = O[q=4g+r][d=16dt+c]
    #pragma unroll
    for (int dt = 0; dt < 4; ++dt)
        #pragma unroll
        for (int r = 0; r < 4; ++r)
            opart[wave][4 * g + r][16 * dt + c] = oacc[dt][r];
    __syncthreads();

    {
        const int q = tid >> 4;            // 0..15
        const int d = (tid & 15) * 4;      // 0..60
        f32x4 o = *(const f32x4*)&opart[0][q][d]
                + *(const f32x4*)&opart[1][q][d]
                + *(const f32x4*)&opart[2][q][d]
                + *(const f32x4*)&opart[3][q][d];
        const float is = inv[q];
        o.x *= is; o.y *= is; o.z *= is; o.w *= is;
        float* Ob = Out + ((size_t)bh * S + q0 + q) * DH + d;
        *(f32x4*)Ob = o;
    }
}

extern "C" void kernel_launch(void* const* d_in, const int* in_sizes, int n_in,
                              void* d_out, int out_size, void* d_ws, size_t ws_size,
                              hipStream_t stream) {
    const float* Q   = (const float*)d_in[0];
    const float* K   = (const float*)d_in[1];
    const float* V   = (const float*)d_in[2];
    const float* Msk = (const float*)d_in[3];

    float* Out = (float*)d_out;                       // [2,16,2048,64]
    float* W   = Out + (size_t)2 * 16 * 2048 * 64;    // [2,16,2048,2048]

    dim3 grid(32 * (S / BQ));
    dim3 block(256);
    hipLaunchKernelGGL(attn_fused, grid, block, 0, stream, Q, K, V, Msk, Out, W);
}

// Round 4
// 455.140 us; speedup vs baseline: 1.4443x; 1.4443x over previous
//
#include <hip/hip_runtime.h>
#include <hip/hip_bf16.h>
#include <stdint.h>

typedef __bf16 bf16;
typedef __attribute__((ext_vector_type(8))) __bf16 bf16x8;
typedef __attribute__((ext_vector_type(4))) float f32x4;

constexpr int S   = 2048;
constexpr int DH  = 64;
constexpr int BQ  = 16;          // q-rows per block
constexpr int NW  = 8;           // waves per block
constexpr int KPW = S / NW;      // 256 keys per wave
constexpr int NC  = KPW / 32;    // 8 chunks of 32 keys

// Fragment conventions (verified in rounds 1-3):
//   mfma(X, Y, acc): X lane(c,g) = X[i=c][k=g*8+j]; Y lane(c,g) = Y[j2=c][k=g*8+j]
//   D lane(c,g) reg r = D[i=g*4+r][j2=c]
// Swapped QK^T mfma(Kfrag, Qfrag): lane(c,g) reg r = P[key=k0+4g+r (r<4) / k0+16+4g+(r-4)][q=c]
//   -> every lane owns ONE q-row (q=c); P slice lives in registers.

__global__ __launch_bounds__(512, 4)
void attn_fused(const float* __restrict__ Q, const float* __restrict__ K,
                const float* __restrict__ V, const float* __restrict__ Msk,
                float* __restrict__ Out, float* __restrict__ W)
{
    __shared__ float rs[NW][BQ];          // per-wave row-sum partials
    __shared__ float inv[BQ];             // 1/rowsum
    __shared__ float opart[NW][BQ][DH];   // per-wave O partials (32 KB)

    const int tid  = threadIdx.x;
    const int lane = tid & 63;
    const int wave = tid >> 6;            // 0..7
    const int c    = lane & 15;
    const int g    = lane >> 4;           // 0..3

    // XCD-aware swizzle: each XCD gets 512 consecutive swz -> 4 contiguous bh
    const int swz = (blockIdx.x & 7) * 512 + (blockIdx.x >> 3);
    const int bh = swz >> 7;              // 0..31
    const int q0 = (swz & 127) * BQ;

    const float* Qb = Q + (size_t)bh * S * DH;
    const float* Kb = K + (size_t)bh * S * DH;
    const float* Vb = V + (size_t)bh * S * DH;

    // ---- Q fragment (Y-operand): lane(c,g) = Q[q0+c][g*8+j], dh halves lo/hi
    bf16x8 qlo, qhi;
    {
        const float* qr = Qb + (size_t)(q0 + c) * DH + g * 8;
        f32x4 a0 = *(const f32x4*)(qr);
        f32x4 a1 = *(const f32x4*)(qr + 4);
        f32x4 b0 = *(const f32x4*)(qr + 32);
        f32x4 b1 = *(const f32x4*)(qr + 36);
        #pragma unroll
        for (int j = 0; j < 4; ++j) {
            qlo[j]     = (bf16)a0[j];  qlo[j + 4] = (bf16)a1[j];
            qhi[j]     = (bf16)b0[j];  qhi[j + 4] = (bf16)b1[j];
        }
    }

    const int kbase = wave * KPW;                     // wave owns 256 keys
    const float* mrow = Msk + (size_t)(q0 + c) * S;   // this lane's q-row of the mask

    // =========== Loop 1: QK^T -> exp -> pa regs + row sums (K read once) ===========
    bf16x8 pa[NC];
    float s = 0.f;
    #pragma unroll
    for (int kc = 0; kc < NC; ++kc) {
        const int k0 = kbase + kc * 32;
        const float* kr0 = Kb + (size_t)(k0 + c) * DH + g * 8;
        const float* kr1 = kr0 + (size_t)16 * DH;
        f32x4 a0 = *(const f32x4*)(kr0);
        f32x4 a1 = *(const f32x4*)(kr0 + 4);
        f32x4 b0 = *(const f32x4*)(kr0 + 32);
        f32x4 b1 = *(const f32x4*)(kr0 + 36);
        f32x4 a2 = *(const f32x4*)(kr1);
        f32x4 a3 = *(const f32x4*)(kr1 + 4);
        f32x4 b2 = *(const f32x4*)(kr1 + 32);
        f32x4 b3 = *(const f32x4*)(kr1 + 36);
        f32x4 m0 = *(const f32x4*)(mrow + k0 + 4 * g);
        f32x4 m1 = *(const f32x4*)(mrow + k0 + 16 + 4 * g);

        bf16x8 kl0, kh0, kl1, kh1;
        #pragma unroll
        for (int j = 0; j < 4; ++j) {
            kl0[j] = (bf16)a0[j];  kl0[j + 4] = (bf16)a1[j];
            kh0[j] = (bf16)b0[j];  kh0[j + 4] = (bf16)b1[j];
            kl1[j] = (bf16)a2[j];  kl1[j + 4] = (bf16)a3[j];
            kh1[j] = (bf16)b2[j];  kh1[j + 4] = (bf16)b3[j];
        }
        f32x4 acc0 = {0.f, 0.f, 0.f, 0.f};
        f32x4 acc1 = {0.f, 0.f, 0.f, 0.f};
        acc0 = __builtin_amdgcn_mfma_f32_16x16x32_bf16(kl0, qlo, acc0, 0, 0, 0);
        acc0 = __builtin_amdgcn_mfma_f32_16x16x32_bf16(kh0, qhi, acc0, 0, 0, 0);
        acc1 = __builtin_amdgcn_mfma_f32_16x16x32_bf16(kl1, qlo, acc1, 0, 0, 0);
        acc1 = __builtin_amdgcn_mfma_f32_16x16x32_bf16(kh1, qhi, acc1, 0, 0, 0);

        #pragma unroll
        for (int r = 0; r < 4; ++r) {
            const float p0 = __expf(acc0[r] * 0.125f + m0[r] * (-1e9f));
            const float p1 = __expf(acc1[r] * 0.125f + m1[r] * (-1e9f));
            s += p0 + p1;
            pa[kc][r]     = (bf16)p0;
            pa[kc][r + 4] = (bf16)p1;
        }
    }

    // reduce over g-groups (same q=c), then across waves
    s += __shfl_xor(s, 16);
    s += __shfl_xor(s, 32);
    if (lane < 16) rs[wave][lane] = s;
    __syncthreads();
    if (tid < BQ) {
        float t = 0.f;
        #pragma unroll
        for (int w = 0; w < NW; ++w) t += rs[w][tid];
        inv[tid] = 1.f / t;
    }
    __syncthreads();
    const float myinv = inv[c];

    // =========== Loop 2: W write (normalized f32) + PV accumulate ===========
    f32x4 oacc[4] = {{0,0,0,0},{0,0,0,0},{0,0,0,0},{0,0,0,0}};
    float* Wrow = W + (size_t)bh * S * S + (size_t)(q0 + c) * S;

    #pragma unroll
    for (int kc = 0; kc < NC; ++kc) {
        const int k0 = kbase + kc * 32;

        // --- W write straight from pa regs (plain stores; L2 merges 64B halves)
        f32x4 w0, w1;
        #pragma unroll
        for (int r = 0; r < 4; ++r) {
            w0[r] = (float)pa[kc][r]     * myinv;
            w1[r] = (float)pa[kc][r + 4] * myinv;
        }
        *(f32x4*)(Wrow + k0 + 4 * g)      = w0;
        *(f32x4*)(Wrow + k0 + 16 + 4 * g) = w1;

        // --- V loads: rows k0+4g+j / k0+16+4g+j, cols c+16*dt (64B-coalesced)
        const float* vp0 = Vb + (size_t)(k0 + 4 * g) * DH + c;
        const float* vp1 = vp0 + (size_t)16 * DH;
        float vv[4][8];
        #pragma unroll
        for (int j = 0; j < 4; ++j) {
            #pragma unroll
            for (int dt = 0; dt < 4; ++dt) {
                vv[dt][j]     = vp0[j * DH + dt * 16];
                vv[dt][j + 4] = vp1[j * DH + dt * 16];
            }
        }
        #pragma unroll
        for (int dt = 0; dt < 4; ++dt) {
            bf16x8 vb;
            #pragma unroll
            for (int j = 0; j < 8; ++j) vb[j] = (bf16)vv[dt][j];
            oacc[dt] = __builtin_amdgcn_mfma_f32_16x16x32_bf16(pa[kc], vb, oacc[dt], 0, 0, 0);
        }
    }

    // --- cross-wave O reduction: lane(c,g) reg r of oacc[dt] = O[q=4g+r][d=16dt+c]
    #pragma unroll
    for (int dt = 0; dt < 4; ++dt)
        #pragma unroll
        for (int r = 0; r < 4; ++r)
            opart[wave][4 * g + r][16 * dt + c] = oacc[dt][r];
    __syncthreads();

    if (tid < BQ * 16) {
        const int q = tid >> 4;            // 0..15
        const int d = (tid & 15) * 4;      // 0..60
        f32x4 o = {0.f, 0.f, 0.f, 0.f};
        #pragma unroll
        for (int w = 0; w < NW; ++w) o += *(const f32x4*)&opart[w][q][d];
        const float is = inv[q];
        o.x *= is; o.y *= is; o.z *= is; o.w *= is;
        float* Ob = Out + ((size_t)bh * S + q0 + q) * DH + d;
        *(f32x4*)Ob = o;
    }
}

extern "C" void kernel_launch(void* const* d_in, const int* in_sizes, int n_in,
                              void* d_out, int out_size, void* d_ws, size_t ws_size,
                              hipStream_t stream) {
    const float* Q   = (const float*)d_in[0];
    const float* K   = (const float*)d_in[1];
    const float* V   = (const float*)d_in[2];
    const float* Msk = (const float*)d_in[3];

    float* Out = (float*)d_out;                       // [2,16,2048,64]
    float* W   = Out + (size_t)2 * 16 * 2048 * 64;    // [2,16,2048,2048]

    dim3 grid(32 * (S / BQ));
    dim3 block(512);
    hipLaunchKernelGGL(attn_fused, grid, block, 0, stream, Q, K, V, Msk, Out, W);
}